// Round 4
// baseline (664.905 us; speedup 1.0000x reference)
//
#include <hip/hip_runtime.h>

#define N_NODES 100000
#define N_EDGES 3200000
#define DIM 128
#define CAP 96   // fixed bucket capacity; Poisson(32) max-degree tail: P(>=96) ~ 1e-18

// ============================ helpers ============================

__device__ __forceinline__ unsigned short f2bf(float f) {   // round-to-nearest-even
    unsigned u = __float_as_uint(f);
    return (unsigned short)((u + 0x7fffu + ((u >> 16) & 1u)) >> 16);
}

// ============================ small utility kernels ============================

__global__ __launch_bounds__(256) void zero_i_kernel(int* __restrict__ p, int n) {
    int i = blockIdx.x * 256 + threadIdx.x;
    if (i < n) p[i] = 0;
}

__global__ __launch_bounds__(256) void zero_f_kernel(float* __restrict__ p, int n) {
    int i = blockIdx.x * 256 + threadIdx.x;
    if (i < n) p[i] = 0.0f;
}

__global__ __launch_bounds__(256) void zero_u64_kernel(unsigned long long* __restrict__ p, int n) {
    int i = blockIdx.x * 256 + threadIdx.x;
    if (i < n) p[i] = 0ull;
}

__global__ __launch_bounds__(256) void zero_f4_kernel(float4* __restrict__ p, int n4) {
    int i = blockIdx.x * 256 + threadIdx.x;
    if (i < n4) p[i] = make_float4(0.f, 0.f, 0.f, 0.f);
}

__global__ __launch_bounds__(256) void dinv_kernel(float* __restrict__ deg) {
    int i = blockIdx.x * 256 + threadIdx.x;
    if (i < N_NODES) deg[i] = rsqrtf(deg[i] + 1.0f);
}

// dinv from packed (count<<40 | deg_fix32)
__global__ __launch_bounds__(256) void dinv_packed_kernel(const unsigned long long* __restrict__ packed,
                                                          float* __restrict__ dinv) {
    int i = blockIdx.x * 256 + threadIdx.x;
    if (i < N_NODES) {
        unsigned long long p = packed[i];
        float deg = (float)(p & 0xFFFFFFFFFFull) * (1.0f / 4294967296.0f);
        dinv[i] = rsqrtf(deg + 1.0f);
    }
}

__global__ __launch_bounds__(256) void wt_kernel(const float* __restrict__ W,
                                                 float* __restrict__ Wt) {
    int idx = blockIdx.x * 256 + threadIdx.x;
    int j = idx >> 7, k = idx & 127;
    Wt[k * 128 + j] = W[idx];
}

// ==================== prep: x->bf16 copy + Wt transpose + packed zero ==========
// heterogeneous grid: [0,6250) bf16 convert, [6250,6314) Wt, [6314,6705) zero

__global__ __launch_bounds__(256) void prep_kernel(const float4* __restrict__ x4,
                                                   ushort4* __restrict__ xh4,
                                                   const float* __restrict__ W,
                                                   float* __restrict__ Wt,
                                                   unsigned long long* __restrict__ packed) {
    const int b = blockIdx.x;
    const int tid = threadIdx.x;
    if (b < 6250) {
        int i0 = b * 512 + tid;
#pragma unroll
        for (int r = 0; r < 2; ++r) {
            int i = i0 + r * 256;            // < 3.2M
            float4 v = x4[i];
            ushort4 h;
            h.x = f2bf(v.x); h.y = f2bf(v.y); h.z = f2bf(v.z); h.w = f2bf(v.w);
            xh4[i] = h;
        }
    } else if (b < 6314) {
        int idx = (b - 6250) * 256 + tid;    // 16384 total
        int j = idx >> 7, k = idx & 127;
        Wt[k * 128 + j] = W[idx];
    } else {
        int i = (b - 6314) * 256 + tid;
        if (i < N_NODES) packed[i] = 0ull;
    }
}

// ==================== one-pass bucket build ====================
// packed[dst] += (1<<40) | fix32(ew)  -> old>>40 is this edge's slot.
// payload (NT store): low32=src, high32=bits(ew)

__global__ __launch_bounds__(256) void bucket_kernel(const int* __restrict__ ei,
                                                     const float* __restrict__ ew,
                                                     unsigned long long* __restrict__ packed,
                                                     long long* __restrict__ ed) {
    int e = blockIdx.x * 256 + threadIdx.x;
    int src = __builtin_nontemporal_load(ei + e);
    int dst = __builtin_nontemporal_load(ei + N_EDGES + e);
    float w = __builtin_nontemporal_load(ew + e);
    unsigned long long inc = (1ull << 40) | (unsigned long long)(w * 4294967296.0f);
    unsigned long long old = atomicAdd(&packed[dst], inc);
    unsigned slot = (unsigned)(old >> 40);
    if (slot < CAP) {
        long long payload = ((long long)__float_as_int(w) << 32) | (unsigned)src;
        __builtin_nontemporal_store(payload, ed + (unsigned)dst * CAP + slot);
    }
}

// ==================== gather over buckets, bf16 x ====================
// One wave per node; lane owns feature pair [2l,2l+1].
// agg[node] = dinv[node] * sum_e (ew_e * dinv[src_e]) * x[src_e]

__global__ __launch_bounds__(256) void gatherb_kernel(const unsigned long long* __restrict__ packed,
                                                      const long long* __restrict__ ed,
                                                      const float* __restrict__ dinv,
                                                      const unsigned* __restrict__ xh,
                                                      float2* __restrict__ agg2) {
    const int wave = threadIdx.x >> 6;
    const int lane = threadIdx.x & 63;
    const int node = blockIdx.x * 4 + wave;

    int cnt = (int)(packed[node] >> 40);
    cnt = min(cnt, CAP);
    const unsigned base = (unsigned)node * CAP;

    float2 acc = make_float2(0.f, 0.f);

    for (int b = 0; b < cnt; b += 64) {
        int idx = b + lane;
        if (idx >= cnt) idx = cnt - 1;       // redundant clamp read
        long long p = __builtin_nontemporal_load(ed + base + idx);
        int msrc = (int)(unsigned)(p & 0xffffffffll);
        float mw  = __int_as_float((int)(p >> 32)) * dinv[msrc];
        int m = min(64, cnt - b);
#pragma unroll 8
        for (int j = 0; j < m; ++j) {
            int s   = __builtin_amdgcn_readlane(msrc, j);
            float w = __int_as_float(__builtin_amdgcn_readlane(__float_as_int(mw), j));
            unsigned v = xh[(unsigned)s * 64u + lane];
            acc.x = fmaf(__uint_as_float(v << 16), w, acc.x);
            acc.y = fmaf(__uint_as_float(v & 0xffff0000u), w, acc.y);
        }
    }

    float di = dinv[node];
    acc.x *= di; acc.y *= di;
    agg2[(unsigned)node * 64u + lane] = acc;
}

// ==================== fallback kernels (f32 bucket / CSR / scatter) ===========

__global__ __launch_bounds__(256) void bucket_f32_kernel(const int* __restrict__ ei,
                                                         const float* __restrict__ ew,
                                                         unsigned long long* __restrict__ packed,
                                                         int2* __restrict__ ed) {
    int e = blockIdx.x * 256 + threadIdx.x;
    int src = ei[e];
    int dst = ei[N_EDGES + e];
    float w = ew[e];
    unsigned long long inc = (1ull << 40) | (unsigned long long)(w * 4294967296.0f);
    unsigned long long old = atomicAdd(&packed[dst], inc);
    unsigned slot = (unsigned)(old >> 40);
    if (slot < CAP) {
        ed[(unsigned)dst * CAP + slot] = make_int2(src, __float_as_int(w));
    }
}

__global__ __launch_bounds__(256) void gatherb_f32_kernel(const unsigned long long* __restrict__ packed,
                                                          const int2* __restrict__ ed,
                                                          const float* __restrict__ dinv,
                                                          const float2* __restrict__ x2,
                                                          float2* __restrict__ agg2) {
    const int wave = threadIdx.x >> 6;
    const int lane = threadIdx.x & 63;
    const int node = blockIdx.x * 4 + wave;

    int cnt = (int)(packed[node] >> 40);
    cnt = min(cnt, CAP);
    const unsigned base = (unsigned)node * CAP;
    float2 acc = make_float2(0.f, 0.f);

    for (int b = 0; b < cnt; b += 64) {
        int idx = b + lane;
        if (idx >= cnt) idx = cnt - 1;
        int2 my = ed[base + idx];
        float wmy = __int_as_float(my.y) * dinv[my.x];
        int m = min(64, cnt - b);
#pragma unroll 8
        for (int j = 0; j < m; ++j) {
            int s = __builtin_amdgcn_readlane(my.x, j);
            float w = __int_as_float(__builtin_amdgcn_readlane(__float_as_int(wmy), j));
            float2 v = x2[(unsigned)s * 64u + lane];
            acc.x = fmaf(v.x, w, acc.x); acc.y = fmaf(v.y, w, acc.y);
        }
    }
    float di = dinv[node];
    acc.x *= di; acc.y *= di;
    agg2[(unsigned)node * 64u + lane] = acc;
}

__global__ __launch_bounds__(256) void count_deg_kernel(const int* __restrict__ ei,
                                                        const float* __restrict__ ew,
                                                        int* __restrict__ count,
                                                        float* __restrict__ deg) {
    int e = blockIdx.x * 256 + threadIdx.x;
    int dst = ei[N_EDGES + e];
    atomicAdd(&count[dst], 1);
    atomicAdd(&deg[dst], ew[e]);
}

__global__ __launch_bounds__(1024) void scan_kernel(const int* __restrict__ count,
                                                    int* __restrict__ row_ptr,
                                                    int* __restrict__ fill) {
    __shared__ int part[1024];
    const int t = threadIdx.x;
    const int chunk = (N_NODES + 1023) / 1024;
    int lo = t * chunk;
    int hi = min(lo + chunk, N_NODES);
    int s = 0;
    for (int i = lo; i < hi; ++i) s += count[i];
    part[t] = s;
    __syncthreads();
    for (int off = 1; off < 1024; off <<= 1) {
        int v = (t >= off) ? part[t - off] : 0;
        __syncthreads();
        part[t] += v;
        __syncthreads();
    }
    int run = part[t] - s;
    for (int i = lo; i < hi; ++i) {
        row_ptr[i] = run;
        fill[i] = run;
        run += count[i];
    }
    if (t == 1023) row_ptr[N_NODES] = part[1023];
}

__global__ __launch_bounds__(256) void fill_kernel(const int* __restrict__ ei,
                                                   const float* __restrict__ ew,
                                                   const float* __restrict__ dinv,
                                                   int* __restrict__ fill,
                                                   int2* __restrict__ ed) {
    int e = blockIdx.x * 256 + threadIdx.x;
    int src = ei[e];
    int dst = ei[N_EDGES + e];
    float w = ew[e] * dinv[src];
    int pos = atomicAdd(&fill[dst], 1);
    ed[pos] = make_int2(src, __float_as_int(w));
}

__global__ __launch_bounds__(256) void gather_kernel(const int* __restrict__ row_ptr,
                                                     const int2* __restrict__ ed,
                                                     const float* __restrict__ dinv,
                                                     const float2* __restrict__ x2,
                                                     float2* __restrict__ agg2) {
    const int wave = threadIdx.x >> 6;
    const int lane = threadIdx.x & 63;
    const int node = blockIdx.x * 4 + wave;
    if (node >= N_NODES) return;

    const int start = row_ptr[node];
    const int end   = row_ptr[node + 1];
    float2 acc = make_float2(0.f, 0.f);

    for (int base = start; base < end; base += 64) {
        int idx = base + lane;
        if (idx >= end) idx = end - 1;
        int2 my = ed[idx];
        int cnt = min(64, end - base);
#pragma unroll 8
        for (int j = 0; j < cnt; ++j) {
            int s = __builtin_amdgcn_readlane(my.x, j);
            float w = __int_as_float(__builtin_amdgcn_readlane(my.y, j));
            float2 v = x2[(unsigned)s * 64u + lane];
            acc.x = fmaf(v.x, w, acc.x); acc.y = fmaf(v.y, w, acc.y);
        }
    }
    float di = dinv[node];
    acc.x *= di; acc.y *= di;
    agg2[(unsigned)node * 64u + lane] = acc;
}

__global__ __launch_bounds__(256) void scatter_kernel(const int* __restrict__ ei,
                                                      const float* __restrict__ ew,
                                                      const float* __restrict__ dinv,
                                                      const float4* __restrict__ x4,
                                                      float* __restrict__ agg) {
    unsigned gid = blockIdx.x * 256u + threadIdx.x;
    unsigned e  = gid >> 5;
    unsigned f4 = gid & 31u;
    int src = ei[e];
    int dst = ei[N_EDGES + e];
    float w = dinv[src] * ew[e] * dinv[dst];
    float4 v = x4[(unsigned)src * 32u + f4];
    float* o = agg + ((unsigned)dst * 128u + f4 * 4u);
    atomicAdd(o + 0, v.x * w);
    atomicAdd(o + 1, v.y * w);
    atomicAdd(o + 2, v.z * w);
    atomicAdd(o + 3, v.w * w);
}

// ============================ fused GEMM + bias + relu + residual =============
// out[i,:] = relu( (agg[i,:] + x[i,:]*dinv[i]^2) @ W^T + bias ) + x[i,:]

__global__ __launch_bounds__(256) void final_kernel(const float* __restrict__ agg_in,
                                                    const float* __restrict__ x,
                                                    const float* __restrict__ bias,
                                                    const float* __restrict__ dinv,
                                                    const float* __restrict__ Wt,
                                                    float* __restrict__ out) {
    __shared__ float sh_wt[16384];
    const int tid = threadIdx.x;
    {
        const float4* s4 = (const float4*)Wt;
        float4* d4 = (float4*)sh_wt;
#pragma unroll
        for (int i = 0; i < 16; ++i) d4[i * 256 + tid] = s4[i * 256 + tid];
    }
    __syncthreads();

    const int wave = tid >> 6;
    const int lane = tid & 63;
    const int rowbase = blockIdx.x * 32 + wave * 8;

    float areg[16];
#pragma unroll
    for (int r = 0; r < 8; ++r) {
        int row = rowbase + r;
        float di = dinv[row];
        float di2 = di * di;
        int base = row * 128;
        areg[2 * r]     = agg_in[base + lane]      + x[base + lane]      * di2;
        areg[2 * r + 1] = agg_in[base + 64 + lane] + x[base + 64 + lane] * di2;
    }

    float acc0[8], acc1[8];
#pragma unroll
    for (int r = 0; r < 8; ++r) { acc0[r] = 0.f; acc1[r] = 0.f; }

    const float2* wt2 = (const float2*)sh_wt;

#pragma unroll
    for (int kh = 0; kh < 2; ++kh) {
#pragma unroll 16
        for (int kk = 0; kk < 64; ++kk) {
            int k = kh * 64 + kk;
            float2 w = wt2[k * 64 + lane];
#pragma unroll
            for (int r = 0; r < 8; ++r) {
                float ak = __uint_as_float(
                    __builtin_amdgcn_readlane(__float_as_uint(areg[2 * r + kh]), kk));
                acc0[r] = fmaf(ak, w.x, acc0[r]);
                acc1[r] = fmaf(ak, w.y, acc1[r]);
            }
        }
    }

    float2 b = ((const float2*)bias)[lane];
#pragma unroll
    for (int r = 0; r < 8; ++r) {
        int row = rowbase + r;
        float2 xr = ((const float2*)x)[row * 64 + lane];
        float v0 = fmaxf(acc0[r] + b.x, 0.f) + xr.x;
        float v1 = fmaxf(acc1[r] + b.y, 0.f) + xr.y;
        ((float2*)out)[row * 64 + lane] = make_float2(v0, v1);
    }
}

// ===============================================================================

extern "C" void kernel_launch(void* const* d_in, const int* in_sizes, int n_in,
                              void* d_out, int out_size, void* d_ws, size_t ws_size,
                              hipStream_t stream) {
    const float* x    = (const float*)d_in[0];
    const float* W    = (const float*)d_in[1];
    const float* bias = (const float*)d_in[2];
    const float* ew   = (const float*)d_in[3];
    const int*   ei   = (const int*)d_in[4];
    float* out = (float*)d_out;
    char* ws = (char*)d_ws;

    // ---------- primary layout ----------
    // packed u64[N]        [0, 800000)
    // dinv  f32[N]         [800000, 1200000)
    // Wt    f32[16384]     [1200000, 1265536)
    // ed    i64[N*CAP]     [1265536, 78065536)
    // xh    bf16[N*128]    [78065536, 103665536)
    unsigned long long* packed = (unsigned long long*)ws;
    float*      dinvA = (float*)(ws + 800000);
    float*      WtA   = (float*)(ws + 1200000);
    long long*  edA   = (long long*)(ws + 1265536);
    unsigned short* xhA = (unsigned short*)(ws + 78065536);
    const size_t WS_BF16   = 103665536ull;
    const size_t WS_BUCKET = 78065536ull;
    const size_t WS_CSR    = 27265552ull;

    if (ws_size >= WS_BF16) {
        prep_kernel<<<6705, 256, 0, stream>>>((const float4*)x, (ushort4*)xhA,
                                              W, WtA, packed);
        bucket_kernel<<<N_EDGES / 256, 256, 0, stream>>>(ei, ew, packed, edA);
        dinv_packed_kernel<<<(N_NODES + 255) / 256, 256, 0, stream>>>(packed, dinvA);
        gatherb_kernel<<<N_NODES / 4, 256, 0, stream>>>(packed, edA, dinvA,
                                                        (const unsigned*)xhA, (float2*)out);
        final_kernel<<<N_NODES / 32, 256, 0, stream>>>(out, x, bias, dinvA, WtA, out);
    } else if (ws_size >= WS_BUCKET) {
        zero_u64_kernel<<<(N_NODES + 255) / 256, 256, 0, stream>>>(packed, N_NODES);
        wt_kernel<<<64, 256, 0, stream>>>(W, WtA);
        bucket_f32_kernel<<<N_EDGES / 256, 256, 0, stream>>>(ei, ew, packed, (int2*)edA);
        dinv_packed_kernel<<<(N_NODES + 255) / 256, 256, 0, stream>>>(packed, dinvA);
        gatherb_f32_kernel<<<N_NODES / 4, 256, 0, stream>>>(packed, (const int2*)edA, dinvA,
                                                            (const float2*)x, (float2*)out);
        final_kernel<<<N_NODES / 32, 256, 0, stream>>>(out, x, bias, dinvA, WtA, out);
    } else if (ws_size >= WS_CSR) {
        float* deg     = (float*)(ws);
        float* Wt      = (float*)(ws + 400000);
        int*   count   = (int*)  (ws + 465536);
        int*   row_ptr = (int*)  (ws + 865536);
        int*   fill    = (int*)  (ws + 1265552);
        int2*  ed      = (int2*) (ws + 1665552);
        zero_f_kernel<<<(N_NODES + 255) / 256, 256, 0, stream>>>(deg, N_NODES);
        wt_kernel<<<64, 256, 0, stream>>>(W, Wt);
        zero_i_kernel<<<(N_NODES + 255) / 256, 256, 0, stream>>>(count, N_NODES);
        count_deg_kernel<<<N_EDGES / 256, 256, 0, stream>>>(ei, ew, count, deg);
        dinv_kernel<<<(N_NODES + 255) / 256, 256, 0, stream>>>(deg);
        scan_kernel<<<1, 1024, 0, stream>>>(count, row_ptr, fill);
        fill_kernel<<<N_EDGES / 256, 256, 0, stream>>>(ei, ew, deg, fill, ed);
        gather_kernel<<<(N_NODES + 3) / 4, 256, 0, stream>>>(row_ptr, ed, deg,
                                                             (const float2*)x, (float2*)out);
        final_kernel<<<N_NODES / 32, 256, 0, stream>>>(out, x, bias, deg, Wt, out);
    } else {
        float* deg   = (float*)(ws);
        float* Wt    = (float*)(ws + 400000);
        int*   count = (int*)  (ws + 465536);
        zero_f_kernel<<<(N_NODES + 255) / 256, 256, 0, stream>>>(deg, N_NODES);
        wt_kernel<<<64, 256, 0, stream>>>(W, Wt);
        zero_f4_kernel<<<(N_NODES * DIM / 4) / 256, 256, 0, stream>>>((float4*)out,
                                                                      N_NODES * DIM / 4);
        count_deg_kernel<<<N_EDGES / 256, 256, 0, stream>>>(ei, ew, count, deg);
        dinv_kernel<<<(N_NODES + 255) / 256, 256, 0, stream>>>(deg);
        scatter_kernel<<<(N_EDGES / 256) * 32, 256, 0, stream>>>(ei, ew, deg,
                                                                 (const float4*)x, out);
        final_kernel<<<N_NODES / 32, 256, 0, stream>>>(out, x, bias, deg, Wt, out);
    }
}

// Round 5
// 475.758 us; speedup vs baseline: 1.3976x; 1.3976x over previous
//
#include <hip/hip_runtime.h>

#define N_NODES 100000
#define N_EDGES 3200000
#define DIM 128

// hierarchical partition geometry
#define NB_C  98       // coarse buckets: dst>>10 (1024 nodes each)
#define CAP_C 36864    // avg 32653, sigma~181 -> +23 sigma
#define NB_F  1568     // fine buckets: 64 nodes each (NB_C*16)
#define CAP_F 2560     // avg 2041, sigma~45 -> +11 sigma
#define CAP   96       // legacy fallback bucket capacity

// payload u64: w_bits[63:32] | dst&1023 [26:17] | src [16:0]

// ============================ helpers ============================

__device__ __forceinline__ unsigned short f2bf(float f) {   // round-to-nearest-even
    unsigned u = __float_as_uint(f);
    return (unsigned short)((u + 0x7fffu + ((u >> 16) & 1u)) >> 16);
}

// ============================ small utility kernels ============================

__global__ __launch_bounds__(256) void zero_i_kernel(int* __restrict__ p, int n) {
    int i = blockIdx.x * 256 + threadIdx.x;
    if (i < n) p[i] = 0;
}

__global__ __launch_bounds__(256) void zero_f_kernel(float* __restrict__ p, int n) {
    int i = blockIdx.x * 256 + threadIdx.x;
    if (i < n) p[i] = 0.0f;
}

__global__ __launch_bounds__(256) void zero_u64_kernel(unsigned long long* __restrict__ p, int n) {
    int i = blockIdx.x * 256 + threadIdx.x;
    if (i < n) p[i] = 0ull;
}

__global__ __launch_bounds__(256) void zero_f4_kernel(float4* __restrict__ p, int n4) {
    int i = blockIdx.x * 256 + threadIdx.x;
    if (i < n4) p[i] = make_float4(0.f, 0.f, 0.f, 0.f);
}

__global__ __launch_bounds__(256) void dinv_kernel(float* __restrict__ deg) {
    int i = blockIdx.x * 256 + threadIdx.x;
    if (i < N_NODES) deg[i] = rsqrtf(deg[i] + 1.0f);
}

__global__ __launch_bounds__(256) void dinv_packed_kernel(const unsigned long long* __restrict__ packed,
                                                          float* __restrict__ dinv) {
    int i = blockIdx.x * 256 + threadIdx.x;
    if (i < N_NODES) {
        unsigned long long p = packed[i];
        float deg = (float)(p & 0xFFFFFFFFFFull) * (1.0f / 4294967296.0f);
        dinv[i] = rsqrtf(deg + 1.0f);
    }
}

__global__ __launch_bounds__(256) void wt_kernel(const float* __restrict__ W,
                                                 float* __restrict__ Wt) {
    int idx = blockIdx.x * 256 + threadIdx.x;
    int j = idx >> 7, k = idx & 127;
    Wt[k * 128 + j] = W[idx];
}

// ==================== prep: bf16 mirror + Wt transpose + zero fill counters ====
// grid: [0,6250) bf16 convert; [6250,6314) Wt; [6314,6321) zero 1666 ints

__global__ __launch_bounds__(256) void prep_kernel(const float4* __restrict__ x4,
                                                   ushort4* __restrict__ xh4,
                                                   const float* __restrict__ W,
                                                   float* __restrict__ Wt,
                                                   int* __restrict__ fills) {
    const int b = blockIdx.x;
    const int tid = threadIdx.x;
    if (b < 6250) {
        int i0 = b * 512 + tid;
#pragma unroll
        for (int r = 0; r < 2; ++r) {
            int i = i0 + r * 256;
            float4 v = x4[i];
            ushort4 h;
            h.x = f2bf(v.x); h.y = f2bf(v.y); h.z = f2bf(v.z); h.w = f2bf(v.w);
            xh4[i] = h;
        }
    } else if (b < 6314) {
        int idx = (b - 6250) * 256 + tid;
        int j = idx >> 7, k = idx & 127;
        Wt[k * 128 + j] = W[idx];
    } else {
        int i = (b - 6314) * 256 + tid;
        if (i < NB_C + NB_F) fills[i] = 0;
    }
}

// ==================== pass A1: edges -> 98 coarse buckets ====================

__global__ __launch_bounds__(256) void partA1_kernel(const int* __restrict__ ei,
                                                     const float* __restrict__ ew,
                                                     int* __restrict__ fill_c,
                                                     unsigned long long* __restrict__ edc) {
    __shared__ int hist[NB_C];
    __shared__ int base[NB_C];
    const int tid = threadIdx.x;
    const int blockbase = blockIdx.x * 4096;
    for (int i = tid; i < NB_C; i += 256) hist[i] = 0;
    __syncthreads();

    unsigned long long pay[16];
    unsigned meta[16];
#pragma unroll
    for (int i = 0; i < 16; ++i) {
        int e = blockbase + i * 256 + tid;
        meta[i] = 0xFFFFFFFFu;
        if (e < N_EDGES) {
            int src = ei[e];
            int dst = ei[N_EDGES + e];
            float w = ew[e];
            int cb = dst >> 10;
            int pos = atomicAdd(&hist[cb], 1);
            pay[i] = ((unsigned long long)__float_as_uint(w) << 32)
                   | ((unsigned)(dst & 1023) << 17) | (unsigned)src;
            meta[i] = ((unsigned)cb << 16) | (unsigned)pos;
        }
    }
    __syncthreads();
    for (int c = tid; c < NB_C; c += 256) {
        int cnt = hist[c];
        base[c] = (cnt > 0) ? atomicAdd(&fill_c[c], cnt) : 0;
    }
    __syncthreads();
#pragma unroll
    for (int i = 0; i < 16; ++i) {
        if (meta[i] != 0xFFFFFFFFu) {
            int cb = (int)(meta[i] >> 16);
            int pos = base[cb] + (int)(meta[i] & 0xFFFFu);
            if (pos < CAP_C)
                edc[(unsigned)cb * CAP_C + (unsigned)pos] = pay[i];
        }
    }
}

// ==================== pass A2: coarse -> 16 fine sub-buckets each ==============
// 9 slice-blocks per coarse bucket (9*4096 >= CAP_C)

__global__ __launch_bounds__(256) void partA2_kernel(const int* __restrict__ fill_c,
                                                     const unsigned long long* __restrict__ edc,
                                                     int* __restrict__ fill_f,
                                                     unsigned long long* __restrict__ edf) {
    __shared__ int hist[16];
    __shared__ int base[16];
    const int tid = threadIdx.x;
    const int cb = blockIdx.x / 9;
    const int lo = (blockIdx.x % 9) * 4096;
    const int cnt_c = min(fill_c[cb], CAP_C);
    const int hi = min(lo + 4096, cnt_c);
    if (tid < 16) hist[tid] = 0;
    __syncthreads();

    unsigned long long pay[16];
    unsigned meta[16];
#pragma unroll
    for (int i = 0; i < 16; ++i) {
        int idx = lo + i * 256 + tid;
        meta[i] = 0xFFFFFFFFu;
        if (idx < hi) {
            unsigned long long p = edc[(unsigned)cb * CAP_C + (unsigned)idx];
            int f = (int)((p >> 23) & 15);      // dst bits [6,10)
            int pos = atomicAdd(&hist[f], 1);
            pay[i] = p;
            meta[i] = ((unsigned)f << 16) | (unsigned)pos;
        }
    }
    __syncthreads();
    if (tid < 16) {
        int c = hist[tid];
        base[tid] = (c > 0) ? atomicAdd(&fill_f[cb * 16 + tid], c) : 0;
    }
    __syncthreads();
#pragma unroll
    for (int i = 0; i < 16; ++i) {
        if (meta[i] != 0xFFFFFFFFu) {
            int f = (int)(meta[i] >> 16);
            int pos = base[f] + (int)(meta[i] & 0xFFFFu);
            if (pos < CAP_F)
                edf[((unsigned)(cb * 16 + f)) * CAP_F + (unsigned)pos] = pay[i];
        }
    }
}

// ==================== pass B: in-place CSR compaction + degree/dinv ===========
// one block per fine bucket (64 nodes); scatter window 20 KB = L2-resident

__global__ __launch_bounds__(256) void partB_kernel(const int* __restrict__ fill_f,
                                                    unsigned long long* __restrict__ edf,
                                                    float* __restrict__ dinv,
                                                    int* __restrict__ row_start,
                                                    int* __restrict__ row_cnt) {
    __shared__ int hist[64];
    __shared__ float degs[64];
    __shared__ int pref[64];
    const int tid = threadIdx.x;
    const int fb = blockIdx.x;
    const int node_base = (fb >> 4) * 1024 + (fb & 15) * 64;
    const int cnt = min(fill_f[fb], CAP_F);
    if (tid < 64) { hist[tid] = 0; degs[tid] = 0.0f; }
    __syncthreads();

    unsigned long long pay[10];
    unsigned meta[10];
    int m = 0;
    for (int idx = tid; idx < cnt; idx += 256) {
        unsigned long long p = edf[(unsigned)fb * CAP_F + (unsigned)idx];
        int dl = (int)((p >> 17) & 63);
        int pos = atomicAdd(&hist[dl], 1);
        atomicAdd(&degs[dl], __uint_as_float((unsigned)(p >> 32)));
        pay[m] = p;
        meta[m] = ((unsigned)dl << 16) | (unsigned)pos;
        ++m;
    }
    __syncthreads();
    if (tid == 0) {
        int run = 0;
#pragma unroll
        for (int n = 0; n < 64; ++n) { pref[n] = run; run += hist[n]; }
    }
    __syncthreads();
    if (tid < 64) {
        int node = node_base + tid;
        if (node < N_NODES) {
            dinv[node] = rsqrtf(degs[tid] + 1.0f);
            row_start[node] = fb * CAP_F + pref[tid];
            row_cnt[node] = hist[tid];
        }
    }
    // all reads completed before the barriers above -> safe in-place compaction
    for (int i = 0; i < m; ++i) {
        int dl = (int)(meta[i] >> 16);
        edf[(unsigned)fb * CAP_F + (unsigned)(pref[dl] + (int)(meta[i] & 0xFFFFu))] = pay[i];
    }
}

// ==================== gather over exact CSR runs, bf16 x ====================

__global__ __launch_bounds__(256) void gatherc_kernel(const int* __restrict__ row_start,
                                                      const int* __restrict__ row_cnt,
                                                      const unsigned long long* __restrict__ edf,
                                                      const float* __restrict__ dinv,
                                                      const unsigned* __restrict__ xh,
                                                      float2* __restrict__ agg2) {
    const int wave = threadIdx.x >> 6;
    const int lane = threadIdx.x & 63;
    const int node = blockIdx.x * 4 + wave;

    const int cnt = row_cnt[node];
    const int start = row_start[node];
    float2 acc = make_float2(0.f, 0.f);

    for (int b = 0; b < cnt; b += 64) {
        int idx = b + lane;
        if (idx >= cnt) idx = cnt - 1;       // redundant clamp read
        unsigned long long p = edf[(unsigned)(start + idx)];
        int msrc = (int)(p & 0x1FFFFull);
        float mw = __uint_as_float((unsigned)(p >> 32)) * dinv[msrc];
        int mcnt = min(64, cnt - b);
#pragma unroll 8
        for (int j = 0; j < mcnt; ++j) {
            int s = __builtin_amdgcn_readlane(msrc, j);
            float w = __int_as_float(__builtin_amdgcn_readlane(__float_as_int(mw), j));
            unsigned v = xh[(unsigned)s * 64u + lane];
            acc.x = fmaf(__uint_as_float(v << 16), w, acc.x);
            acc.y = fmaf(__uint_as_float(v & 0xffff0000u), w, acc.y);
        }
    }

    float di = dinv[node];
    acc.x *= di; acc.y *= di;
    agg2[(unsigned)node * 64u + lane] = acc;
}

// ==================== fallback kernels (f32 bucket / CSR / scatter) ===========

__global__ __launch_bounds__(256) void bucket_f32_kernel(const int* __restrict__ ei,
                                                         const float* __restrict__ ew,
                                                         unsigned long long* __restrict__ packed,
                                                         int2* __restrict__ ed) {
    int e = blockIdx.x * 256 + threadIdx.x;
    int src = ei[e];
    int dst = ei[N_EDGES + e];
    float w = ew[e];
    unsigned long long inc = (1ull << 40) | (unsigned long long)(w * 4294967296.0f);
    unsigned long long old = atomicAdd(&packed[dst], inc);
    unsigned slot = (unsigned)(old >> 40);
    if (slot < CAP) {
        ed[(unsigned)dst * CAP + slot] = make_int2(src, __float_as_int(w));
    }
}

__global__ __launch_bounds__(256) void gatherb_f32_kernel(const unsigned long long* __restrict__ packed,
                                                          const int2* __restrict__ ed,
                                                          const float* __restrict__ dinv,
                                                          const float2* __restrict__ x2,
                                                          float2* __restrict__ agg2) {
    const int wave = threadIdx.x >> 6;
    const int lane = threadIdx.x & 63;
    const int node = blockIdx.x * 4 + wave;

    int cnt = (int)(packed[node] >> 40);
    cnt = min(cnt, CAP);
    const unsigned base = (unsigned)node * CAP;
    float2 acc = make_float2(0.f, 0.f);

    for (int b = 0; b < cnt; b += 64) {
        int idx = b + lane;
        if (idx >= cnt) idx = cnt - 1;
        int2 my = ed[base + idx];
        float wmy = __int_as_float(my.y) * dinv[my.x];
        int m = min(64, cnt - b);
#pragma unroll 8
        for (int j = 0; j < m; ++j) {
            int s = __builtin_amdgcn_readlane(my.x, j);
            float w = __int_as_float(__builtin_amdgcn_readlane(__float_as_int(wmy), j));
            float2 v = x2[(unsigned)s * 64u + lane];
            acc.x = fmaf(v.x, w, acc.x); acc.y = fmaf(v.y, w, acc.y);
        }
    }
    float di = dinv[node];
    acc.x *= di; acc.y *= di;
    agg2[(unsigned)node * 64u + lane] = acc;
}

__global__ __launch_bounds__(256) void count_deg_kernel(const int* __restrict__ ei,
                                                        const float* __restrict__ ew,
                                                        int* __restrict__ count,
                                                        float* __restrict__ deg) {
    int e = blockIdx.x * 256 + threadIdx.x;
    int dst = ei[N_EDGES + e];
    atomicAdd(&count[dst], 1);
    atomicAdd(&deg[dst], ew[e]);
}

__global__ __launch_bounds__(256) void scatter_kernel(const int* __restrict__ ei,
                                                      const float* __restrict__ ew,
                                                      const float* __restrict__ dinv,
                                                      const float4* __restrict__ x4,
                                                      float* __restrict__ agg) {
    unsigned gid = blockIdx.x * 256u + threadIdx.x;
    unsigned e  = gid >> 5;
    unsigned f4 = gid & 31u;
    int src = ei[e];
    int dst = ei[N_EDGES + e];
    float w = dinv[src] * ew[e] * dinv[dst];
    float4 v = x4[(unsigned)src * 32u + f4];
    float* o = agg + ((unsigned)dst * 128u + f4 * 4u);
    atomicAdd(o + 0, v.x * w);
    atomicAdd(o + 1, v.y * w);
    atomicAdd(o + 2, v.z * w);
    atomicAdd(o + 3, v.w * w);
}

// ============================ fused GEMM + bias + relu + residual =============
// out[i,:] = relu( (agg[i,:] + x[i,:]*dinv[i]^2) @ W^T + bias ) + x[i,:]

__global__ __launch_bounds__(256) void final_kernel(const float* __restrict__ agg_in,
                                                    const float* __restrict__ x,
                                                    const float* __restrict__ bias,
                                                    const float* __restrict__ dinv,
                                                    const float* __restrict__ Wt,
                                                    float* __restrict__ out) {
    __shared__ float sh_wt[16384];
    const int tid = threadIdx.x;
    {
        const float4* s4 = (const float4*)Wt;
        float4* d4 = (float4*)sh_wt;
#pragma unroll
        for (int i = 0; i < 16; ++i) d4[i * 256 + tid] = s4[i * 256 + tid];
    }
    __syncthreads();

    const int wave = tid >> 6;
    const int lane = tid & 63;
    const int rowbase = blockIdx.x * 32 + wave * 8;

    float areg[16];
#pragma unroll
    for (int r = 0; r < 8; ++r) {
        int row = rowbase + r;
        float di = dinv[row];
        float di2 = di * di;
        int base = row * 128;
        areg[2 * r]     = agg_in[base + lane]      + x[base + lane]      * di2;
        areg[2 * r + 1] = agg_in[base + 64 + lane] + x[base + 64 + lane] * di2;
    }

    float acc0[8], acc1[8];
#pragma unroll
    for (int r = 0; r < 8; ++r) { acc0[r] = 0.f; acc1[r] = 0.f; }

    const float2* wt2 = (const float2*)sh_wt;

#pragma unroll
    for (int kh = 0; kh < 2; ++kh) {
#pragma unroll 16
        for (int kk = 0; kk < 64; ++kk) {
            int k = kh * 64 + kk;
            float2 w = wt2[k * 64 + lane];
#pragma unroll
            for (int r = 0; r < 8; ++r) {
                float ak = __uint_as_float(
                    __builtin_amdgcn_readlane(__float_as_uint(areg[2 * r + kh]), kk));
                acc0[r] = fmaf(ak, w.x, acc0[r]);
                acc1[r] = fmaf(ak, w.y, acc1[r]);
            }
        }
    }

    float2 b = ((const float2*)bias)[lane];
#pragma unroll
    for (int r = 0; r < 8; ++r) {
        int row = rowbase + r;
        float2 xr = ((const float2*)x)[row * 64 + lane];
        float v0 = fmaxf(acc0[r] + b.x, 0.f) + xr.x;
        float v1 = fmaxf(acc1[r] + b.y, 0.f) + xr.y;
        ((float2*)out)[row * 64 + lane] = make_float2(v0, v1);
    }
}

// ===============================================================================

extern "C" void kernel_launch(void* const* d_in, const int* in_sizes, int n_in,
                              void* d_out, int out_size, void* d_ws, size_t ws_size,
                              hipStream_t stream) {
    const float* x    = (const float*)d_in[0];
    const float* W    = (const float*)d_in[1];
    const float* bias = (const float*)d_in[2];
    const float* ew   = (const float*)d_in[3];
    const int*   ei   = (const int*)d_in[4];
    float* out = (float*)d_out;
    char* ws = (char*)d_ws;

    // ---------- primary layout (hierarchical partition) ----------
    // xh bf16[N*128]       [0, 25600000)
    // Wt f32[16384]        [25600000, 25665536)
    // dinv f32[N]          [25665536, 26065536)
    // row_start int[N]     [26065536, 26465536)
    // row_cnt int[N]       [26465536, 26865536)
    // fill_c int[98]       [26865536, ...) contiguous with fill_f int[1568]
    // edc u64[98*36864]    [26872256, 55773632)
    // edf u64[1568*2560]   [55773632, 87886272)
    unsigned short* xhA  = (unsigned short*)ws;
    float* WtA       = (float*)(ws + 25600000);
    float* dinvA     = (float*)(ws + 25665536);
    int*   row_start = (int*)  (ws + 26065536);
    int*   row_cnt   = (int*)  (ws + 26465536);
    int*   fill_c    = (int*)  (ws + 26865536);
    int*   fill_f    = fill_c + NB_C;
    unsigned long long* edc = (unsigned long long*)(ws + 26872256);
    unsigned long long* edf = (unsigned long long*)(ws + 55773632);
    const size_t WS_PART = 87886272ull;

    // ---------- fallback layout (round-3 bucket) ----------
    unsigned long long* packed = (unsigned long long*)ws;
    float* dinvB = (float*)(ws + 800000);
    float* WtB   = (float*)(ws + 1200000);
    int2*  edB   = (int2*)(ws + 1265536);
    const size_t WS_BUCKET = 1265536ull + (size_t)N_NODES * CAP * 8ull;   // ~78.1 MB

    if (ws_size >= WS_PART) {
        prep_kernel<<<6321, 256, 0, stream>>>((const float4*)x, (ushort4*)xhA,
                                              W, WtA, fill_c);
        partA1_kernel<<<(N_EDGES + 4095) / 4096, 256, 0, stream>>>(ei, ew, fill_c, edc);
        partA2_kernel<<<NB_C * 9, 256, 0, stream>>>(fill_c, edc, fill_f, edf);
        partB_kernel<<<NB_F, 256, 0, stream>>>(fill_f, edf, dinvA, row_start, row_cnt);
        gatherc_kernel<<<N_NODES / 4, 256, 0, stream>>>(row_start, row_cnt, edf, dinvA,
                                                        (const unsigned*)xhA, (float2*)out);
        final_kernel<<<N_NODES / 32, 256, 0, stream>>>(out, x, bias, dinvA, WtA, out);
    } else if (ws_size >= WS_BUCKET) {
        zero_u64_kernel<<<(N_NODES + 255) / 256, 256, 0, stream>>>(packed, N_NODES);
        wt_kernel<<<64, 256, 0, stream>>>(W, WtB);
        bucket_f32_kernel<<<N_EDGES / 256, 256, 0, stream>>>(ei, ew, packed, edB);
        dinv_packed_kernel<<<(N_NODES + 255) / 256, 256, 0, stream>>>(packed, dinvB);
        gatherb_f32_kernel<<<N_NODES / 4, 256, 0, stream>>>(packed, edB, dinvB,
                                                            (const float2*)x, (float2*)out);
        final_kernel<<<N_NODES / 32, 256, 0, stream>>>(out, x, bias, dinvB, WtB, out);
    } else {
        float* deg   = (float*)(ws);
        float* Wt    = (float*)(ws + 400000);
        int*   count = (int*)  (ws + 465536);
        zero_f_kernel<<<(N_NODES + 255) / 256, 256, 0, stream>>>(deg, N_NODES);
        zero_i_kernel<<<(N_NODES + 255) / 256, 256, 0, stream>>>(count, N_NODES);
        wt_kernel<<<64, 256, 0, stream>>>(W, Wt);
        zero_f4_kernel<<<(N_NODES * DIM / 4) / 256, 256, 0, stream>>>((float4*)out,
                                                                      N_NODES * DIM / 4);
        count_deg_kernel<<<N_EDGES / 256, 256, 0, stream>>>(ei, ew, count, deg);
        dinv_kernel<<<(N_NODES + 255) / 256, 256, 0, stream>>>(deg);
        scatter_kernel<<<(N_EDGES / 256) * 32, 256, 0, stream>>>(ei, ew, deg,
                                                                 (const float4*)x, out);
        final_kernel<<<N_NODES / 32, 256, 0, stream>>>(out, x, bias, deg, Wt, out);
    }
}